// Round 6
// baseline (3947.867 us; speedup 1.0000x reference)
//
#include <hip/hip_runtime.h>
#include <hip/hip_bf16.h>

// LiftSplatShoot voxel pooling, B=1, N=6, D=41, H=64, W=176, C=32, grid 200x200x1.
// nprime = 2,770,944 points. voxel = ix*200 + iy. out[c*40000+v] = sum x[p][c].
// Inputs f32, OUTPUT f32. PASSED R5 at 3921 us, but WRITE_SIZE=2.2GB showed
// agent-scope f32 atomics punt every 4B RMW past the (non-coherent) per-XCD L2
// at ~18.7 G atomics/s.
//
// R5 -> R6: per-XCD privatized accumulators. 8 copies (41 MB in d_ws) indexed
// by the hardware XCC_ID; unsafeAtomicAdd (global_atomic_add_f32, no sc bits)
// executes in the LOCAL XCD L2 -- correct because each line is only dirtied by
// one XCD, and kernel-end flush / kernel-start invalidate publishes the copies
// to the reduce kernel. Reduce sums 8 copies + transposes to (C,200,200).

#define NVOX 40000
#define NCH  32
#define NXCD 8

__device__ __forceinline__ unsigned xcd_id() {
    unsigned x;
    asm volatile("s_getreg_b32 %0, hwreg(HW_REG_XCC_ID)" : "=s"(x));
    return x & (NXCD - 1);
}

__global__ void __launch_bounds__(256)
lss_scatter(const float* __restrict__ geom,
            const float* __restrict__ x,
            float* __restrict__ acc, int nprime, int c0, int cg) {
    int p = blockIdx.x * blockDim.x + threadIdx.x;
    if (p >= nprime) return;

    // Exact reference arithmetic: t = (g - (bx - dx/2)) / dx, trunc toward zero.
    float gx = geom[3 * (size_t)p + 0];
    float gy = geom[3 * (size_t)p + 1];
    float gz = geom[3 * (size_t)p + 2];

    float tx = (gx + 50.0f) / 0.5f;   // exact
    float ty = (gy + 50.0f) / 0.5f;   // exact
    float tz = (gz + 10.0f) / 20.0f;  // correctly-rounded IEEE f32 division

    int ix = (int)tx;  // trunc toward zero == numpy astype(int32); (-1,0)->0 kept
    int iy = (int)ty;
    int iz = (int)tz;

    if (!((ix >= 0) && (ix < 200) && (iy >= 0) && (iy < 200) && (iz == 0))) return;

    int v = ix * 200 + iy;
    float* dst = acc + ((size_t)xcd_id() * NVOX + v) * cg;
    const float* row = x + (size_t)p * NCH + c0;

    int k4 = cg >> 2;                       // cg is a power of 2
    const float4* rv = (const float4*)row;  // 16B-aligned (c0 multiple of cg>=4)
    for (int k = 0; k < k4; ++k) {
        float4 q = rv[k];
        unsafeAtomicAdd(dst + 4 * k + 0, q.x);  // XCD-local L2 atomic
        unsafeAtomicAdd(dst + 4 * k + 1, q.y);
        unsafeAtomicAdd(dst + 4 * k + 2, q.z);
        unsafeAtomicAdd(dst + 4 * k + 3, q.w);
    }
    for (int k = k4 << 2; k < cg; ++k)      // cg in {1,2} safety fallback
        unsafeAtomicAdd(dst + k, row[k]);
}

// Sum the 8 per-XCD copies and transpose: out[(c0+c)*NVOX + s] = sum_k acc[k][s][c].
// Per-thread: 8 * cg contiguous f32 reads (coalesced float4), cg coalesced writes.
__global__ void __launch_bounds__(256)
lss_reduce(const float* __restrict__ acc, float* __restrict__ out, int c0, int cg) {
    int s = blockIdx.x * blockDim.x + threadIdx.x;
    if (s >= NVOX) return;

    float sum[NCH];
    for (int c = 0; c < cg; ++c) sum[c] = 0.0f;

    for (int k = 0; k < NXCD; ++k) {
        const float* src = acc + ((size_t)k * NVOX + s) * cg;
        int k4 = cg >> 2;
        const float4* sv = (const float4*)src;
        for (int q = 0; q < k4; ++q) {
            float4 w = sv[q];
            sum[4 * q + 0] += w.x;
            sum[4 * q + 1] += w.y;
            sum[4 * q + 2] += w.z;
            sum[4 * q + 3] += w.w;
        }
        for (int c = k4 << 2; c < cg; ++c) sum[c] += src[c];
    }
    for (int c = 0; c < cg; ++c)
        out[(size_t)(c0 + c) * NVOX + s] = sum[c];
}

extern "C" void kernel_launch(void* const* d_in, const int* in_sizes, int n_in,
                              void* d_out, int out_size, void* d_ws, size_t ws_size,
                              hipStream_t stream) {
    const float* geom = (const float*)d_in[0];
    const float* x    = (const float*)d_in[1];
    int gsz = in_sizes[0], xsz = in_sizes[1];
    if (gsz > xsz) {  // defensive: geom (nprime*3) is the smaller input
        const float* tmp = geom; geom = x; x = tmp;
        int t2 = gsz; gsz = xsz; xsz = t2;
    }
    float* acc = (float*)d_ws;
    float* out = (float*)d_out;

    int nprime = xsz / NCH;  // 2,770,944

    // Largest power-of-2 channel group s.t. 8 copies fit in ws.
    // ws >= 5.12 MB (R5 evidence) -> cg >= 4; cg == 32 if ws >= 41 MB.
    int cg = NCH;
    while (cg > 1 && (size_t)NXCD * NVOX * cg * sizeof(float) > ws_size) cg >>= 1;

    int threads = 256;
    int blocks_scatter = (nprime + threads - 1) / threads;
    int blocks_reduce  = (NVOX + threads - 1) / threads;

    for (int c0 = 0; c0 < NCH; c0 += cg) {
        hipMemsetAsync(acc, 0, (size_t)NXCD * NVOX * cg * sizeof(float), stream);
        lss_scatter<<<blocks_scatter, threads, 0, stream>>>(geom, x, acc, nprime, c0, cg);
        lss_reduce<<<blocks_reduce, threads, 0, stream>>>(acc, out, c0, cg);
    }
}